// Round 10
// baseline (143.084 us; speedup 1.0000x reference)
//
#include <hip/hip_runtime.h>
#include <hip/hip_bf16.h>

// GCK 3x3 conv == plain 3x3 conv with W_eff = basis · linCombs.
// FUSED implicit GEMM: M=O=64, N=512*512, K=C*9=576, bf16 MFMA 16x16x32.
// R9: chunk-size probe. 1024 blocks = 256 row-tiles(2 out rows) x 4 col-tiles
// (128 px). 512 threads (8 waves -> 4/SIMD). Staging loads are float2 with all
// 64 lanes covering 128 consecutive cols -> 512B contiguous per instruction
// (vs 256B in R8, testing the DRAM-efficiency hypothesis for the 2.3 TB/s
// plateau). LDS = 4 rows x 130 cols x 64 ch bf16 (66.5 KB) -> 2 blocks/CU.
// XCD-chunked: xcd=bid&7 -> ct=xcd&3, rt banded; vertical halo in-XCD L2.

constexpr int kC = 64, kO = 64;
constexpr int kH = 514, kW = 514;
constexpr int kHO = 512, kWO = 512;
constexpr int kNPIX = kH * kW;          // 264196
constexpr int LCOLS = 130;

typedef __attribute__((ext_vector_type(8))) short short8;    // 8 bf16
typedef __attribute__((ext_vector_type(4))) float floatx4;   // 4 fp32 acc

__device__ inline unsigned short f2bf(float f) {
    unsigned int u = __float_as_uint(f);
    unsigned int r = (u + 0x7fffu + ((u >> 16) & 1u)) >> 16;  // RN-even
    return (unsigned short)r;
}

// ---------------------------------------------------------------- weight prep
// W_eff[o,c,3r+s] = sum_{i,j} lin[o, c*9+3i+j] * V[i,r]*V[j,s]
// stored pre-swizzled into MFMA A-fragment order:
//   kglob = tap*64 + c ; ks = kglob>>5 ; kg = (kglob>>3)&3 ; e = kglob&7
//   w2[ ((ks*4+kg)*64 + o)*8 + e ] = bf16(W_eff)
__global__ void gck_wprep(const float* __restrict__ lin, unsigned short* __restrict__ w2) {
    int t = blockIdx.x * 256 + threadIdx.x;
    if (t >= kO * kC * 9) return;
    int tap = t % 9;
    int c   = (t / 9) % kC;
    int o   = t / (9 * kC);
    int r = tap / 3, s = tap % 3;
    const float Vm[3][3] = {{1.f, 1.f, 1.f}, {1.f, -1.f, 1.f}, {1.f, 1.f, -1.f}};
    float acc = 0.f;
#pragma unroll
    for (int i = 0; i < 3; i++)
#pragma unroll
        for (int j = 0; j < 3; j++)
            acc += lin[o * (kC * 9) + c * 9 + 3 * i + j] * Vm[i][r] * Vm[j][s];
    int kglob = tap * 64 + c;
    int ks = kglob >> 5, kg = (kglob >> 3) & 3, e = kglob & 7;
    w2[((ks * 4 + kg) * 64 + o) * 8 + e] = f2bf(acc);
}

// ------------------------------------------------------------- fused conv
__global__ __launch_bounds__(512, 4) void gck_conv(const float* __restrict__ x,
                                                   const unsigned short* __restrict__ w2,
                                                   float* __restrict__ out) {
    __shared__ unsigned short xs[4 * LCOLS * 64];   // 66,560 B -> 2 blocks/CU

    const int bid = blockIdx.x;               // 0..1023
    const int xcd = bid & 7;
    const int ct  = xcd & 3;                  // column stripe, fixed per XCD
    const int rt  = (xcd >> 2) * 128 + (bid >> 3);
    const int hbase = rt * 2;
    const int wbase = ct * 128;
    const int t    = threadIdx.x;
    const int wave = t >> 6;
    const int lane = t & 63;
    const int l16  = lane & 15;
    const int kg   = lane >> 4;

    // ---- stage 4 input rows: thread owns octet u = wave (8 ch), col-pair cp.
    // Per instruction: 64 lanes cover 128 consecutive cols -> 512B runs.
    {
        const int cp  = t & 63;
        const int u   = t >> 6;               // ch-octet 0..7
        const int ch0 = u * 8;
#pragma unroll
        for (int r = 0; r < 4; ++r) {
            const float* gp = x + (size_t)(hbase + r) * kW + wbase + cp * 2;
            float2 f[8];
#pragma unroll
            for (int e = 0; e < 8; ++e)
                f[e] = *reinterpret_cast<const float2*>(gp + (size_t)(ch0 + e) * kNPIX);
#pragma unroll
            for (int j = 0; j < 2; ++j) {
                int col = cp * 2 + j;
                short8 u8;
#pragma unroll
                for (int e = 0; e < 8; ++e) u8[e] = (short)f2bf(j ? f[e].y : f[e].x);
                int swz = (u ^ (col & 7) ^ ((col >> 3) & 7)) & 7;
                *reinterpret_cast<short8*>(&xs[(r * LCOLS + col) * 64 + swz * 8]) = u8;
            }
        }
        // halo cols 128,129 : 4 rows x 64 ch x 2 cols = 512 elements, 1/thread
        {
            int col = 128 + (t & 1);
            int ch  = (t >> 1) & 63;
            int r   = t >> 7;
            float f = x[(size_t)ch * kNPIX + (size_t)(hbase + r) * kW + wbase + col];
            int swz = ((ch >> 3) ^ (col & 7) ^ ((col >> 3) & 7)) & 7;
            xs[(r * LCOLS + col) * 64 + swz * 8 + (ch & 7)] = f2bf(f);
        }
    }
    __syncthreads();

    // ---- compute: wave = (hw, px-quarter): 1h x 32px x 64o, acc 4m x 2n
    const int hw  = wave >> 2;                // local output row 0..1
    const int px0 = (wave & 3) * 32;

    floatx4 acc[4][2];
#pragma unroll
    for (int m = 0; m < 4; m++)
#pragma unroll
        for (int n = 0; n < 2; n++) acc[m][n] = (floatx4){0.f, 0.f, 0.f, 0.f};

    const short8* w2v = reinterpret_cast<const short8*>(w2);

    // A prefetch (global, L2-resident 72 KiB, broadcast across waves)
    short8 a_cur[4];
#pragma unroll
    for (int m = 0; m < 4; m++) a_cur[m] = w2v[(0 * 4 + kg) * 64 + m * 16 + l16];

#pragma unroll 2
    for (int ks = 0; ks < 18; ++ks) {
        int tap = ks >> 1;
        int r0  = tap / 3;
        int s   = tap - r0 * 3;

        short8 a_nxt[4];
        int ksn = (ks < 17) ? ks + 1 : ks;
#pragma unroll
        for (int m = 0; m < 4; m++) a_nxt[m] = w2v[(ksn * 4 + kg) * 64 + m * 16 + l16];

        int rr = hw + r0;                      // staged row 0..3
        int u2 = (ks & 1) * 4 + kg;            // 16B ch-octet 0..7
        short8 b[2];
#pragma unroll
        for (int n = 0; n < 2; ++n) {
            int col = px0 + n * 16 + l16 + s;  // 0..129
            int swz = (u2 ^ (col & 7) ^ ((col >> 3) & 7)) & 7;
            b[n] = *reinterpret_cast<const short8*>(&xs[(rr * LCOLS + col) * 64 + swz * 8]);
        }

#pragma unroll
        for (int m = 0; m < 4; m++)
#pragma unroll
            for (int n = 0; n < 2; n++)
                acc[m][n] = __builtin_amdgcn_mfma_f32_16x16x32_bf16(a_cur[m], b[n], acc[m][n], 0, 0, 0);

#pragma unroll
        for (int m = 0; m < 4; m++) a_cur[m] = a_nxt[m];
    }

    // epilogue: D row(o) = m*16 + kg*4 + j, col(px) = wbase + px0 + n*16 + l16
    const int h = hbase + hw;
#pragma unroll
    for (int m = 0; m < 4; m++) {
#pragma unroll
        for (int n = 0; n < 2; n++) {
            int wcol = wbase + px0 + n * 16 + l16;
#pragma unroll
            for (int j = 0; j < 4; j++) {
                int o = m * 16 + kg * 4 + j;
                out[((size_t)o * kHO + h) * kWO + wcol] = acc[m][n][j];
            }
        }
    }
}

extern "C" void kernel_launch(void* const* d_in, const int* in_sizes, int n_in,
                              void* d_out, int out_size, void* d_ws, size_t ws_size,
                              hipStream_t stream) {
    const float* x   = (const float*)d_in[0];   // (1,64,514,514) fp32
    const float* lin = (const float*)d_in[1];   // (64,576) fp32
    float* out = (float*)d_out;                 // (1,64,512,512) fp32

    unsigned short* w2 = (unsigned short*)d_ws; // 72 KiB

    gck_wprep<<<(kO * kC * 9 + 255) / 256, 256, 0, stream>>>(lin, w2);
    gck_conv<<<1024, 512, 0, stream>>>(x, w2, out);
}